// Round 1
// baseline (66.085 us; speedup 1.0000x reference)
//
#include <hip/hip_runtime.h>

// Problem: B=2048, N=8192, F=512, H=8, F_=64
// Key identity: softmax_n(e1[b]+e2[n]) == softmax_n(e2[n])  (row-constant shift cancels)
// => attn independent of b => out[b, h*64+e] = relu( (p[h] @ G) @ W[h] )[e], broadcast over b.
// X/WhX/e1/a1 never affect the output.
//
// Pipeline (all f32, deterministic):
//   K1: w2[h][f]   = sum_e W[h,f,e] * att[h,64+e]                  (8x512)
//   K2: e2[h][n]   = G[n,:] . w2[h,:]                              (8x8192)  pass 1 over G
//   K3: p_t[n][h]  = softmax over n of e2[h][:]                    (8192x8)
//   K4: part[b][h][f] = sum_{n in chunk b} p[n,h]*G[n,f]           (128x8x512) pass 2 over G
//   K5: g[h][f]    = sum_b part[b][h][f]                           (8x512)
//   K6: vr[h][e]   = relu( sum_f g[h,f]*W[h,f,e] )                 (8x64)
//   K7: out[b][:]  = vr[:]  broadcast                              (2048x512)

#define HF 8
#define FDIM 512
#define FE 64
#define NG 8192
#define BX 2048
#define NB4 128   // blocks in K4 (rows per block = NG/NB4 = 64)

__global__ __launch_bounds__(256) void k1_w2(const float* __restrict__ W,
                                             const float* __restrict__ att,
                                             float* __restrict__ w2) {
    int id = blockIdx.x * 256 + threadIdx.x;      // 0..4095
    int h = id >> 9, f = id & 511;
    const float* a2 = att + h * (2 * FE) + FE;    // att[h, 64:]
    const float* wp = W + ((size_t)(h * FDIM + f)) * FE;
    float s = 0.f;
#pragma unroll
    for (int e = 0; e < FE; e += 4) {
        float4 w4 = *reinterpret_cast<const float4*>(wp + e);
        s += w4.x * a2[e] + w4.y * a2[e + 1] + w4.z * a2[e + 2] + w4.w * a2[e + 3];
    }
    w2[id] = s;
}

__global__ __launch_bounds__(256) void k2_e2(const float* __restrict__ G,
                                             const float* __restrict__ w2g,
                                             float* __restrict__ e2) {
    __shared__ float w2s[HF * FDIM];              // 16 KiB
    for (int i = threadIdx.x; i < HF * FDIM; i += 256) w2s[i] = w2g[i];
    __syncthreads();

    int wave = threadIdx.x >> 6;                  // 0..3, one row per wave
    int lane = threadIdx.x & 63;
    int n = blockIdx.x * 4 + wave;

    const float* gp = G + (size_t)n * FDIM + lane * 8;
    float4 g0 = *reinterpret_cast<const float4*>(gp);
    float4 g1 = *reinterpret_cast<const float4*>(gp + 4);

    float acc[HF];
#pragma unroll
    for (int h = 0; h < HF; ++h) {
        const float* w = w2s + h * FDIM + lane * 8;
        float4 w0 = *reinterpret_cast<const float4*>(w);
        float4 w1 = *reinterpret_cast<const float4*>(w + 4);
        acc[h] = g0.x * w0.x + g0.y * w0.y + g0.z * w0.z + g0.w * w0.w
               + g1.x * w1.x + g1.y * w1.y + g1.z * w1.z + g1.w * w1.w;
    }
    // full 64-lane butterfly; after this every lane holds the row totals
#pragma unroll
    for (int off = 32; off > 0; off >>= 1) {
#pragma unroll
        for (int h = 0; h < HF; ++h) acc[h] += __shfl_xor(acc[h], off, 64);
    }
    if (lane == 0) {
#pragma unroll
        for (int h = 0; h < HF; ++h) e2[h * NG + n] = acc[h];
    }
}

__global__ __launch_bounds__(256) void k3_softmax(const float* __restrict__ e2,
                                                  float* __restrict__ pt) {
    int h = blockIdx.x;
    const float* e = e2 + (size_t)h * NG;
    int t = threadIdx.x, lane = t & 63, wv = t >> 6;

    __shared__ float sm[4];
    __shared__ float ss[4];

    float m = -1e30f;
    for (int n = t; n < NG; n += 256) m = fmaxf(m, e[n]);
#pragma unroll
    for (int off = 32; off > 0; off >>= 1) m = fmaxf(m, __shfl_xor(m, off, 64));
    if (lane == 0) sm[wv] = m;
    __syncthreads();
    m = fmaxf(fmaxf(sm[0], sm[1]), fmaxf(sm[2], sm[3]));

    float s = 0.f;
    for (int n = t; n < NG; n += 256) s += expf(e[n] - m);
#pragma unroll
    for (int off = 32; off > 0; off >>= 1) s += __shfl_xor(s, off, 64);
    if (lane == 0) ss[wv] = s;
    __syncthreads();
    s = ss[0] + ss[1] + ss[2] + ss[3];
    float inv = 1.0f / s;

    for (int n = t; n < NG; n += 256) pt[(size_t)n * HF + h] = expf(e[n] - m) * inv;
}

__global__ __launch_bounds__(256) void k4_gpart(const float* __restrict__ G,
                                                const float* __restrict__ pt,
                                                float* __restrict__ part) {
    int b = blockIdx.x;              // 0..NB4-1
    int t = threadIdx.x;             // owns f = 2t, 2t+1
    float acc[HF][2] = {};
    int n0 = b * (NG / NB4);
    for (int r = 0; r < NG / NB4; ++r) {
        int n = n0 + r;
        float2 gv = *reinterpret_cast<const float2*>(G + (size_t)n * FDIM + t * 2);
        float4 p0 = *reinterpret_cast<const float4*>(pt + (size_t)n * HF);
        float4 p1 = *reinterpret_cast<const float4*>(pt + (size_t)n * HF + 4);
        float ph[HF] = {p0.x, p0.y, p0.z, p0.w, p1.x, p1.y, p1.z, p1.w};
#pragma unroll
        for (int h = 0; h < HF; ++h) {
            acc[h][0] += ph[h] * gv.x;
            acc[h][1] += ph[h] * gv.y;
        }
    }
    float* dst = part + (size_t)b * (HF * FDIM);
#pragma unroll
    for (int h = 0; h < HF; ++h) {
        float2 v = make_float2(acc[h][0], acc[h][1]);
        *reinterpret_cast<float2*>(dst + h * FDIM + t * 2) = v;
    }
}

__global__ __launch_bounds__(256) void k5_gred(const float* __restrict__ part,
                                               float* __restrict__ g) {
    int i = blockIdx.x * 256 + threadIdx.x;       // 0..4095
    float s = 0.f;
    for (int b = 0; b < NB4; ++b) s += part[(size_t)b * (HF * FDIM) + i];
    g[i] = s;
}

__global__ __launch_bounds__(64) void k6_v(const float* __restrict__ g,
                                           const float* __restrict__ W,
                                           float* __restrict__ vr) {
    int h = blockIdx.x, e = threadIdx.x;          // one wave per head
    const float* gp = g + h * FDIM;
    const float* wp = W + (size_t)h * FDIM * FE + e;
    float s = 0.f;
    for (int f = 0; f < FDIM; ++f) s += gp[f] * wp[(size_t)f * FE];
    vr[h * FE + e] = fmaxf(s, 0.f);
}

__global__ __launch_bounds__(256) void k7_bcast(const float* __restrict__ vr,
                                                float* __restrict__ out) {
    int idx = blockIdx.x * 256 + threadIdx.x;     // 2048*128 float4 stores
    int c = idx & 127;
    float4 v = reinterpret_cast<const float4*>(vr)[c];
    reinterpret_cast<float4*>(out)[idx] = v;
}

extern "C" void kernel_launch(void* const* d_in, const int* in_sizes, int n_in,
                              void* d_out, int out_size, void* d_ws, size_t ws_size,
                              hipStream_t stream) {
    // inputs: 0=X (unused!), 1=G, 2=W, 3=att
    const float* G   = (const float*)d_in[1];
    const float* W   = (const float*)d_in[2];
    const float* att = (const float*)d_in[3];
    float* out = (float*)d_out;

    float* ws   = (float*)d_ws;
    float* w2   = ws;                         // 4096
    float* e2   = w2 + HF * FDIM;             // 65536
    float* pt   = e2 + HF * NG;               // 65536
    float* part = pt + NG * HF;               // 128*4096 = 524288
    float* g    = part + (size_t)NB4 * HF * FDIM;  // 4096
    float* vr   = g + HF * FDIM;              // 512
    // total ws use: ~2.66 MB (floats)

    hipLaunchKernelGGL(k1_w2,      dim3(16),   dim3(256), 0, stream, W, att, w2);
    hipLaunchKernelGGL(k2_e2,      dim3(NG/4), dim3(256), 0, stream, G, w2, e2);
    hipLaunchKernelGGL(k3_softmax, dim3(HF),   dim3(256), 0, stream, e2, pt);
    hipLaunchKernelGGL(k4_gpart,   dim3(NB4),  dim3(256), 0, stream, G, pt, part);
    hipLaunchKernelGGL(k5_gred,    dim3(16),   dim3(256), 0, stream, part, g);
    hipLaunchKernelGGL(k6_v,       dim3(HF),   dim3(64),  0, stream, g, W, vr);
    hipLaunchKernelGGL(k7_bcast,   dim3(BX/2), dim3(256), 0, stream, vr, out);
}